// Round 1
// baseline (1678.458 us; speedup 1.0000x reference)
//
#include <hip/hip_runtime.h>
#include <hip/hip_bf16.h>

#define DM 1024
#define SLEN 2048
#define MROWS 4096   // B*S
#define QKVLD 3072

typedef short  short8 __attribute__((ext_vector_type(8)));
typedef float  f32x4  __attribute__((ext_vector_type(4)));
typedef unsigned short u16x4 __attribute__((ext_vector_type(4)));

__device__ __forceinline__ unsigned short f2bf(float f) {
  __hip_bfloat16 h = __float2bfloat16(f);
  return __builtin_bit_cast(unsigned short, h);
}

__device__ __forceinline__ void gload16(const void* g, void* l) {
  __builtin_amdgcn_global_load_lds(
      (const __attribute__((address_space(1))) unsigned int*)g,
      (__attribute__((address_space(3))) unsigned int*)l, 16, 0, 0);
}

// ---------------- Weight transpose + fp32->bf16 convert ----------------
// W[K][N] fp32 -> Wt[N][K] bf16.  32x32 tiles via LDS.
__global__ __launch_bounds__(256) void transpose_cvt(
    const float* __restrict__ W, unsigned short* __restrict__ Wt, int K, int N)
{
  __shared__ float t[32][33];
  const int k0 = blockIdx.y * 32, n0 = blockIdx.x * 32;
  const int tid = threadIdx.x;
  const int row = tid >> 3, c4 = (tid & 7) * 4;
  const float4 v = *(const float4*)&W[(size_t)(k0 + row) * N + n0 + c4];
  t[row][c4 + 0] = v.x; t[row][c4 + 1] = v.y;
  t[row][c4 + 2] = v.z; t[row][c4 + 3] = v.w;
  __syncthreads();
  u16x4 ov;
  #pragma unroll
  for (int j = 0; j < 4; ++j) ov[j] = f2bf(t[c4 + j][row]);
  *(u16x4*)&Wt[(size_t)(n0 + row) * K + k0 + c4] = ov;
}

// ---------------- LayerNorm (fp32 in, bf16 out) ----------------
__global__ __launch_bounds__(256) void ln_kernel(
    const float* __restrict__ x, const float* __restrict__ g,
    const float* __restrict__ b, unsigned short* __restrict__ h)
{
  const int row = blockIdx.x, tid = threadIdx.x;
  const float4 v = ((const float4*)(x + (size_t)row * DM))[tid];
  float s  = v.x + v.y + v.z + v.w;
  float ss = v.x * v.x + v.y * v.y + v.z * v.z + v.w * v.w;
  #pragma unroll
  for (int m = 32; m >= 1; m >>= 1) {
    s  += __shfl_xor(s,  m, 64);
    ss += __shfl_xor(ss, m, 64);
  }
  __shared__ float red[8];
  const int w = tid >> 6, lane = tid & 63;
  if (lane == 0) { red[w] = s; red[4 + w] = ss; }
  __syncthreads();
  s  = red[0] + red[1] + red[2] + red[3];
  ss = red[4] + red[5] + red[6] + red[7];
  const float mu  = s * (1.f / DM);
  const float var = ss * (1.f / DM) - mu * mu;
  const float rs  = rsqrtf(var + 1e-5f);
  const float4 gv = ((const float4*)g)[tid];
  const float4 bv = ((const float4*)b)[tid];
  u16x4 o;
  o[0] = f2bf((v.x - mu) * rs * gv.x + bv.x);
  o[1] = f2bf((v.y - mu) * rs * gv.y + bv.y);
  o[2] = f2bf((v.z - mu) * rs * gv.z + bv.z);
  o[3] = f2bf((v.w - mu) * rs * gv.w + bv.w);
  ((u16x4*)(h + (size_t)row * DM))[tid] = o;
}

// ---------------- bias concat (bq|bk|bv -> 3072) ----------------
__global__ void concat3(const float* __restrict__ a, const float* __restrict__ b,
                        const float* __restrict__ c, float* __restrict__ out)
{
  const int i = blockIdx.x * 256 + threadIdx.x;
  out[i] = (i < 1024) ? a[i] : (i < 2048 ? b[i - 1024] : c[i - 2048]);
}

// ---------------- GEMM: C[M][N] = A[M][K](bf16) @ Bt[N][K]^T(bf16) + bias ----------------
// m97 structure: 128x128 tile, BK=32, 4 waves (2x2), 4x4 16x16x32 frags/wave,
// global_load_lds width-16 staging.
template<int RELU, int RESID>
__global__ __launch_bounds__(256) void gemm_bt(
    const unsigned short* __restrict__ A,
    const unsigned short* __restrict__ Bt,
    const float* __restrict__ bias,
    const float* __restrict__ res,
    float* __restrict__ outf,
    unsigned short* __restrict__ outb,
    int M, int N, int K)
{
  __shared__ short Al[128 * 32];
  __shared__ short Bl[128 * 32];
  const int tid = threadIdx.x;
  const int w = tid >> 6, lane = tid & 63;
  const int m0 = blockIdx.y * 128, n0 = blockIdx.x * 128;
  const int wr = (w >> 1) * 64, wc = (w & 1) * 64;
  const int r16 = lane & 15, g4 = lane >> 4;

  f32x4 acc[4][4];
  #pragma unroll
  for (int i = 0; i < 4; ++i)
    #pragma unroll
    for (int j = 0; j < 4; ++j) acc[i][j] = (f32x4){0.f, 0.f, 0.f, 0.f};

  for (int kt = 0; kt < K; kt += 32) {
    #pragma unroll
    for (int i = 0; i < 2; ++i) {
      const int chunk = (i * 4 + w) * 64 + lane;   // 0..511
      const int row = chunk >> 2, off = (chunk & 3) * 8;
      gload16(&A[(size_t)(m0 + row) * K + kt + off], &Al[chunk * 8]);
      gload16(&Bt[(size_t)(n0 + row) * K + kt + off], &Bl[chunk * 8]);
    }
    __syncthreads();
    short8 af[4], bfr[4];
    #pragma unroll
    for (int mi = 0; mi < 4; ++mi)
      af[mi] = *(const short8*)&Al[(wr + mi * 16 + r16) * 32 + g4 * 8];
    #pragma unroll
    for (int ni = 0; ni < 4; ++ni)
      bfr[ni] = *(const short8*)&Bl[(wc + ni * 16 + r16) * 32 + g4 * 8];
    #pragma unroll
    for (int mi = 0; mi < 4; ++mi)
      #pragma unroll
      for (int ni = 0; ni < 4; ++ni)
        acc[mi][ni] = __builtin_amdgcn_mfma_f32_16x16x32_bf16(af[mi], bfr[ni], acc[mi][ni], 0, 0, 0);
    __syncthreads();
  }

  #pragma unroll
  for (int ni = 0; ni < 4; ++ni) {
    const int col = n0 + wc + ni * 16 + r16;
    const float bv = bias[col];
    #pragma unroll
    for (int mi = 0; mi < 4; ++mi) {
      #pragma unroll
      for (int j = 0; j < 4; ++j) {
        const int row = m0 + wr + mi * 16 + g4 * 4 + j;
        float v = acc[mi][ni][j] + bv;
        if (RELU) v = fmaxf(v, 0.f);
        const size_t idx = (size_t)row * N + col;
        if (RESID) outf[idx] = res[idx] + v;
        else       outb[idx] = f2bf(v);
      }
    }
  }
}

// ---------------- Flash attention ----------------
// grid (S/64 q-tiles, B*H). 4 waves x 16 q-rows. KT=64 keys/iter staged in LDS.
__global__ __launch_bounds__(256) void attn_kernel(
    const unsigned short* __restrict__ qkv,   // [B*S][3072] (q|k|v)
    unsigned short* __restrict__ o)           // [B*S][1024]
{
  __shared__ short Kl[64 * 80];
  __shared__ short Vl[64 * 80];
  __shared__ short Pl[4 * 16 * 80];
  const int tid = threadIdx.x;
  const int w = tid >> 6, lane = tid & 63;
  const int r16 = lane & 15, g4 = lane >> 4;
  const int qt = blockIdx.x;
  const int bb = blockIdx.y >> 4, hh = blockIdx.y & 15;
  const size_t rowbase = (size_t)bb * SLEN;
  const short* qp = (const short*)qkv;

  short8 qf[2];
  {
    const size_t qrow = rowbase + qt * 64 + w * 16 + r16;
    #pragma unroll
    for (int kk = 0; kk < 2; ++kk)
      qf[kk] = *(const short8*)&qp[qrow * QKVLD + hh * 64 + kk * 32 + g4 * 8];
  }

  f32x4 oacc[4];
  #pragma unroll
  for (int i = 0; i < 4; ++i) oacc[i] = (f32x4){0.f, 0.f, 0.f, 0.f};
  float m_prev[4], l_acc[4];
  #pragma unroll
  for (int j = 0; j < 4; ++j) { m_prev[j] = -1e30f; l_acc[j] = 0.f; }

  for (int kt = 0; kt < SLEN / 64; ++kt) {
    // stage K,V tiles (64 keys x 64 dims, stride 80 to dodge bank conflicts)
    #pragma unroll
    for (int i = 0; i < 2; ++i) {
      const int c = tid + i * 256;        // 0..511
      const int row = c >> 3, off = (c & 7) * 8;
      const size_t grow = rowbase + kt * 64 + row;
      *(short8*)&Kl[row * 80 + off] = *(const short8*)&qp[grow * QKVLD + 1024 + hh * 64 + off];
      *(short8*)&Vl[row * 80 + off] = *(const short8*)&qp[grow * QKVLD + 2048 + hh * 64 + off];
    }
    __syncthreads();

    // S = Q K^T * scale  (4 key sub-tiles of 16)
    f32x4 sf[4];
    #pragma unroll
    for (int kf = 0; kf < 4; ++kf) {
      f32x4 accs = (f32x4){0.f, 0.f, 0.f, 0.f};
      #pragma unroll
      for (int kk = 0; kk < 2; ++kk) {
        const short8 kfr = *(const short8*)&Kl[(kf * 16 + r16) * 80 + kk * 32 + g4 * 8];
        accs = __builtin_amdgcn_mfma_f32_16x16x32_bf16(qf[kk], kfr, accs, 0, 0, 0);
      }
      sf[kf] = accs * 0.125f;
    }

    // online softmax (rows = g4*4+j, cols across 16-lane group)
    float mnew[4], fscale[4];
    #pragma unroll
    for (int j = 0; j < 4; ++j) {
      float tm = fmaxf(fmaxf(sf[0][j], sf[1][j]), fmaxf(sf[2][j], sf[3][j]));
      #pragma unroll
      for (int mm = 8; mm >= 1; mm >>= 1) tm = fmaxf(tm, __shfl_xor(tm, mm, 64));
      mnew[j] = fmaxf(m_prev[j], tm);
      fscale[j] = __expf(m_prev[j] - mnew[j]);
    }
    float rsum[4] = {0.f, 0.f, 0.f, 0.f};
    #pragma unroll
    for (int kf = 0; kf < 4; ++kf)
      #pragma unroll
      for (int j = 0; j < 4; ++j) {
        const float p = __expf(sf[kf][j] - mnew[j]);
        rsum[j] += p;
        Pl[w * 1280 + (g4 * 4 + j) * 80 + kf * 16 + r16] = (short)f2bf(p);
      }
    #pragma unroll
    for (int j = 0; j < 4; ++j) {
      float r = rsum[j];
      #pragma unroll
      for (int mm = 8; mm >= 1; mm >>= 1) r += __shfl_xor(r, mm, 64);
      l_acc[j] = l_acc[j] * fscale[j] + r;
      m_prev[j] = mnew[j];
    }
    #pragma unroll
    for (int hf = 0; hf < 4; ++hf)
      #pragma unroll
      for (int j = 0; j < 4; ++j) oacc[hf][j] *= fscale[j];

    // O += P V   (P read back from per-wave LDS in A-layout)
    #pragma unroll
    for (int kk = 0; kk < 2; ++kk) {
      const short8 pf = *(const short8*)&Pl[w * 1280 + r16 * 80 + kk * 32 + g4 * 8];
      #pragma unroll
      for (int hf = 0; hf < 4; ++hf) {
        short8 vf;
        #pragma unroll
        for (int i = 0; i < 8; ++i)
          vf[i] = Vl[(kk * 32 + g4 * 8 + i) * 80 + hf * 16 + r16];
        oacc[hf] = __builtin_amdgcn_mfma_f32_16x16x32_bf16(pf, vf, oacc[hf], 0, 0, 0);
      }
    }
    __syncthreads();
  }

  #pragma unroll
  for (int hf = 0; hf < 4; ++hf)
    #pragma unroll
    for (int j = 0; j < 4; ++j) {
      const float val = oacc[hf][j] / l_acc[j];
      const size_t orow = rowbase + qt * 64 + w * 16 + g4 * 4 + j;
      o[orow * DM + hh * 64 + hf * 16 + r16] = f2bf(val);
    }
}

// ---------------- launcher ----------------
extern "C" void kernel_launch(void* const* d_in, const int* in_sizes, int n_in,
                              void* d_out, int out_size, void* d_ws, size_t ws_size,
                              hipStream_t stream) {
  const float* x_in = (const float*)d_in[0];
  const float* Wq = (const float*)d_in[1];  const float* bq = (const float*)d_in[2];
  const float* Wk = (const float*)d_in[3];  const float* bk = (const float*)d_in[4];
  const float* Wv = (const float*)d_in[5];  const float* bv = (const float*)d_in[6];
  const float* Wo = (const float*)d_in[7];  const float* bo = (const float*)d_in[8];
  const float* W1 = (const float*)d_in[9];  const float* b1 = (const float*)d_in[10];
  const float* W2 = (const float*)d_in[11]; const float* b2 = (const float*)d_in[12];
  const float* ln1g = (const float*)d_in[13]; const float* ln1b = (const float*)d_in[14];
  const float* ln2g = (const float*)d_in[15]; const float* ln2b = (const float*)d_in[16];

  const size_t MB = 1u << 20;
  char* ws = (char*)d_ws;
  float*          x   = (float*)(ws + 0);                 // 16 MB fp32 residual
  unsigned short* h   = (unsigned short*)(ws + 16 * MB);  // 8 MB bf16 LN out
  unsigned short* qkv = (unsigned short*)(ws + 24 * MB);  // 24 MB bf16 [4096][3072]
  unsigned short* ob  = (unsigned short*)(ws + 48 * MB);  // 8 MB bf16 attn out
  unsigned short* f1  = (unsigned short*)(ws + 56 * MB);  // 32 MB bf16 ffn mid
  unsigned short* wt  = (unsigned short*)(ws + 88 * MB);  // 8 MB bf16 transposed W
  float*          b3  = (float*)(ws + 96 * MB);           // 12 KB qkv bias

  hipMemcpyAsync(x, x_in, (size_t)MROWS * DM * sizeof(float),
                 hipMemcpyDeviceToDevice, stream);

  for (int i = 0; i < 4; ++i) {
    const size_t DD = (size_t)DM * DM;
    // --- attention sublayer ---
    ln_kernel<<<MROWS, 256, 0, stream>>>(x, ln1g + i * DM, ln1b + i * DM, h);
    transpose_cvt<<<dim3(32, 32), 256, 0, stream>>>(Wq + i * DD, wt,                 DM, DM);
    transpose_cvt<<<dim3(32, 32), 256, 0, stream>>>(Wk + i * DD, wt + 1024 * 1024,   DM, DM);
    transpose_cvt<<<dim3(32, 32), 256, 0, stream>>>(Wv + i * DD, wt + 2048 * 1024,   DM, DM);
    concat3<<<12, 256, 0, stream>>>(bq + i * DM, bk + i * DM, bv + i * DM, b3);
    gemm_bt<0, 0><<<dim3(QKVLD / 128, MROWS / 128), 256, 0, stream>>>(
        h, wt, b3, nullptr, nullptr, qkv, MROWS, QKVLD, DM);
    attn_kernel<<<dim3(SLEN / 64, 32), 256, 0, stream>>>(qkv, ob);
    transpose_cvt<<<dim3(32, 32), 256, 0, stream>>>(Wo + i * DD, wt, DM, DM);
    gemm_bt<0, 1><<<dim3(DM / 128, MROWS / 128), 256, 0, stream>>>(
        ob, wt, bo + i * DM, x, x, nullptr, MROWS, DM, DM);
    // --- FFN sublayer ---
    ln_kernel<<<MROWS, 256, 0, stream>>>(x, ln2g + i * DM, ln2b + i * DM, h);
    transpose_cvt<<<dim3(128, 32), 256, 0, stream>>>(W1 + i * 4 * DD, wt, DM, 4 * DM);
    gemm_bt<1, 0><<<dim3(4 * DM / 128, MROWS / 128), 256, 0, stream>>>(
        h, wt, b1 + i * 4 * DM, nullptr, nullptr, f1, MROWS, 4 * DM, DM);
    transpose_cvt<<<dim3(32, 128), 256, 0, stream>>>(W2 + i * 4 * DD, wt, 4 * DM, DM);
    gemm_bt<0, 1><<<dim3(DM / 128, MROWS / 128), 256, 0, stream>>>(
        f1, wt, b2 + i * DM, x, x, nullptr, MROWS, DM, 4 * DM);
  }

  hipMemcpyAsync(d_out, x, (size_t)MROWS * DM * sizeof(float),
                 hipMemcpyDeviceToDevice, stream);
}

// Round 2
// 1539.720 us; speedup vs baseline: 1.0901x; 1.0901x over previous
//
#include <hip/hip_runtime.h>
#include <hip/hip_bf16.h>

#define DM 1024
#define SLEN 2048
#define MROWS 4096   // B*S
#define QKVLD 3072

typedef short  short8 __attribute__((ext_vector_type(8)));
typedef float  f32x4  __attribute__((ext_vector_type(4)));
typedef unsigned short u16x4 __attribute__((ext_vector_type(4)));

__device__ __forceinline__ unsigned short f2bf(float f) {
  __hip_bfloat16 h = __float2bfloat16(f);
  return __builtin_bit_cast(unsigned short, h);
}

__device__ __forceinline__ void gload16(const void* g, void* l) {
  __builtin_amdgcn_global_load_lds(
      (const __attribute__((address_space(1))) unsigned int*)g,
      (__attribute__((address_space(3))) unsigned int*)l, 16, 0, 0);
}

// ---------------- Weight transpose + fp32->bf16 convert ----------------
// W[K][N] fp32 -> Wt[N][K] bf16.  32x32 tiles via LDS.
__global__ __launch_bounds__(256) void transpose_cvt(
    const float* __restrict__ W, unsigned short* __restrict__ Wt, int K, int N)
{
  __shared__ float t[32][33];
  const int k0 = blockIdx.y * 32, n0 = blockIdx.x * 32;
  const int tid = threadIdx.x;
  const int row = tid >> 3, c4 = (tid & 7) * 4;
  const float4 v = *(const float4*)&W[(size_t)(k0 + row) * N + n0 + c4];
  t[row][c4 + 0] = v.x; t[row][c4 + 1] = v.y;
  t[row][c4 + 2] = v.z; t[row][c4 + 3] = v.w;
  __syncthreads();
  u16x4 ov;
  #pragma unroll
  for (int j = 0; j < 4; ++j) ov[j] = f2bf(t[c4 + j][row]);
  *(u16x4*)&Wt[(size_t)(n0 + row) * K + k0 + c4] = ov;
}

// ---------------- V transpose: qkv V-cols -> Vt[bh][64][2048] (bf16) ----------------
__global__ __launch_bounds__(256) void vtrans(
    const unsigned short* __restrict__ qkv, unsigned short* __restrict__ vt)
{
  __shared__ unsigned short t[32][40];
  const int bh = blockIdx.z;                    // 0..31
  const int b = bh >> 4, h = bh & 15;
  const int s0 = blockIdx.y * 32, d0 = blockIdx.x * 32;
  const int tid = threadIdx.x;
  const int row = tid >> 3, c4 = (tid & 7) * 4;
  const u16x4 v = *(const u16x4*)&qkv[(size_t)(b * SLEN + s0 + row) * QKVLD + 2048 + h * 64 + d0 + c4];
  t[row][c4 + 0] = v[0]; t[row][c4 + 1] = v[1];
  t[row][c4 + 2] = v[2]; t[row][c4 + 3] = v[3];
  __syncthreads();
  u16x4 ov;
  #pragma unroll
  for (int j = 0; j < 4; ++j) ov[j] = t[c4 + j][row];
  *(u16x4*)&vt[((size_t)bh * 64 + d0 + row) * SLEN + s0 + c4] = ov;
}

// ---------------- LayerNorm (fp32 in, bf16 out) ----------------
__global__ __launch_bounds__(256) void ln_kernel(
    const float* __restrict__ x, const float* __restrict__ g,
    const float* __restrict__ b, unsigned short* __restrict__ h)
{
  const int row = blockIdx.x, tid = threadIdx.x;
  const float4 v = ((const float4*)(x + (size_t)row * DM))[tid];
  float s  = v.x + v.y + v.z + v.w;
  float ss = v.x * v.x + v.y * v.y + v.z * v.z + v.w * v.w;
  #pragma unroll
  for (int m = 32; m >= 1; m >>= 1) {
    s  += __shfl_xor(s,  m, 64);
    ss += __shfl_xor(ss, m, 64);
  }
  __shared__ float red[8];
  const int w = tid >> 6, lane = tid & 63;
  if (lane == 0) { red[w] = s; red[4 + w] = ss; }
  __syncthreads();
  s  = red[0] + red[1] + red[2] + red[3];
  ss = red[4] + red[5] + red[6] + red[7];
  const float mu  = s * (1.f / DM);
  const float var = ss * (1.f / DM) - mu * mu;
  const float rs  = rsqrtf(var + 1e-5f);
  const float4 gv = ((const float4*)g)[tid];
  const float4 bv = ((const float4*)b)[tid];
  u16x4 o;
  o[0] = f2bf((v.x - mu) * rs * gv.x + bv.x);
  o[1] = f2bf((v.y - mu) * rs * gv.y + bv.y);
  o[2] = f2bf((v.z - mu) * rs * gv.z + bv.z);
  o[3] = f2bf((v.w - mu) * rs * gv.w + bv.w);
  ((u16x4*)(h + (size_t)row * DM))[tid] = o;
}

// ---------------- bias concat (bq|bk|bv -> 3072) ----------------
__global__ void concat3(const float* __restrict__ a, const float* __restrict__ b,
                        const float* __restrict__ c, float* __restrict__ out)
{
  const int i = blockIdx.x * 256 + threadIdx.x;
  out[i] = (i < 1024) ? a[i] : (i < 2048 ? b[i - 1024] : c[i - 2048]);
}

// ---------------- GEMM: C[M][N] = A[M][K](bf16) @ Bt[N][K]^T(bf16) + bias ----------------
template<int RELU, int RESID>
__global__ __launch_bounds__(256) void gemm_bt(
    const unsigned short* __restrict__ A,
    const unsigned short* __restrict__ Bt,
    const float* __restrict__ bias,
    const float* __restrict__ res,
    float* __restrict__ outf,
    unsigned short* __restrict__ outb,
    int M, int N, int K)
{
  __shared__ short Al[128 * 32];
  __shared__ short Bl[128 * 32];
  const int tid = threadIdx.x;
  const int w = tid >> 6, lane = tid & 63;
  const int m0 = blockIdx.y * 128, n0 = blockIdx.x * 128;
  const int wr = (w >> 1) * 64, wc = (w & 1) * 64;
  const int r16 = lane & 15, g4 = lane >> 4;

  f32x4 acc[4][4];
  #pragma unroll
  for (int i = 0; i < 4; ++i)
    #pragma unroll
    for (int j = 0; j < 4; ++j) acc[i][j] = (f32x4){0.f, 0.f, 0.f, 0.f};

  for (int kt = 0; kt < K; kt += 32) {
    #pragma unroll
    for (int i = 0; i < 2; ++i) {
      const int chunk = (i * 4 + w) * 64 + lane;   // 0..511
      const int row = chunk >> 2, off = (chunk & 3) * 8;
      gload16(&A[(size_t)(m0 + row) * K + kt + off], &Al[chunk * 8]);
      gload16(&Bt[(size_t)(n0 + row) * K + kt + off], &Bl[chunk * 8]);
    }
    __syncthreads();
    short8 af[4], bfr[4];
    #pragma unroll
    for (int mi = 0; mi < 4; ++mi)
      af[mi] = *(const short8*)&Al[(wr + mi * 16 + r16) * 32 + g4 * 8];
    #pragma unroll
    for (int ni = 0; ni < 4; ++ni)
      bfr[ni] = *(const short8*)&Bl[(wc + ni * 16 + r16) * 32 + g4 * 8];
    #pragma unroll
    for (int mi = 0; mi < 4; ++mi)
      #pragma unroll
      for (int ni = 0; ni < 4; ++ni)
        acc[mi][ni] = __builtin_amdgcn_mfma_f32_16x16x32_bf16(af[mi], bfr[ni], acc[mi][ni], 0, 0, 0);
    __syncthreads();
  }

  #pragma unroll
  for (int ni = 0; ni < 4; ++ni) {
    const int col = n0 + wc + ni * 16 + r16;
    const float bv = bias[col];
    #pragma unroll
    for (int mi = 0; mi < 4; ++mi) {
      #pragma unroll
      for (int j = 0; j < 4; ++j) {
        const int row = m0 + wr + mi * 16 + g4 * 4 + j;
        float v = acc[mi][ni][j] + bv;
        if (RELU) v = fmaxf(v, 0.f);
        const size_t idx = (size_t)row * N + col;
        if (RESID) outf[idx] = res[idx] + v;
        else       outb[idx] = f2bf(v);
      }
    }
  }
}

// ---------------- Flash attention ----------------
// grid (S/64 q-tiles, B*H). 4 waves x 16 q-rows. KT=64 keys/iter staged in LDS.
// K staged row-major [key][d] (stride 72); V staged pre-transposed [d][key] (stride 72).
#define LSTR 72
__global__ __launch_bounds__(256) void attn_kernel(
    const unsigned short* __restrict__ qkv,   // [B*S][3072] (q|k|v)
    const unsigned short* __restrict__ vt,    // [B*H][64][2048]
    unsigned short* __restrict__ o)           // [B*S][1024]
{
  __shared__ short Kl[64 * LSTR];
  __shared__ short Vl[64 * LSTR];   // transposed: [d][key]
  __shared__ short Pl[4 * 16 * LSTR];
  const int tid = threadIdx.x;
  const int w = tid >> 6, lane = tid & 63;
  const int r16 = lane & 15, g4 = lane >> 4;
  const int qt = blockIdx.x;
  const int bh = blockIdx.y;
  const int hh = bh & 15;
  const size_t rowbase = (size_t)(bh >> 4) * SLEN;
  const short* qp = (const short*)qkv;
  const short* vp = (const short*)(vt + (size_t)bh * 64 * SLEN);

  short8 qf[2];
  {
    const size_t qrow = rowbase + qt * 64 + w * 16 + r16;
    #pragma unroll
    for (int kk = 0; kk < 2; ++kk)
      qf[kk] = *(const short8*)&qp[qrow * QKVLD + hh * 64 + kk * 32 + g4 * 8];
  }

  f32x4 oacc[4];
  #pragma unroll
  for (int i = 0; i < 4; ++i) oacc[i] = (f32x4){0.f, 0.f, 0.f, 0.f};
  float m_prev[4], l_acc[4];
  #pragma unroll
  for (int j = 0; j < 4; ++j) { m_prev[j] = -1e30f; l_acc[j] = 0.f; }

  for (int kt = 0; kt < SLEN / 64; ++kt) {
    // stage K (row-major) and Vt (transposed) tiles
    #pragma unroll
    for (int i = 0; i < 2; ++i) {
      const int c = tid + i * 256;        // 0..511
      const int row = c >> 3, off = (c & 7) * 8;
      *(short8*)&Kl[row * LSTR + off] =
          *(const short8*)&qp[(rowbase + kt * 64 + row) * QKVLD + 1024 + hh * 64 + off];
      *(short8*)&Vl[row * LSTR + off] =
          *(const short8*)&vp[(size_t)row * SLEN + kt * 64 + off];
    }
    __syncthreads();

    // S = Q K^T * scale  (4 key sub-tiles of 16)
    f32x4 sf[4];
    #pragma unroll
    for (int kf = 0; kf < 4; ++kf) {
      f32x4 accs = (f32x4){0.f, 0.f, 0.f, 0.f};
      #pragma unroll
      for (int kk = 0; kk < 2; ++kk) {
        const short8 kfr = *(const short8*)&Kl[(kf * 16 + r16) * LSTR + kk * 32 + g4 * 8];
        accs = __builtin_amdgcn_mfma_f32_16x16x32_bf16(qf[kk], kfr, accs, 0, 0, 0);
      }
      sf[kf] = accs * 0.125f;
    }

    // online softmax (rows = g4*4+j, cols across 16-lane group)
    float mnew[4], fscale[4];
    #pragma unroll
    for (int j = 0; j < 4; ++j) {
      float tm = fmaxf(fmaxf(sf[0][j], sf[1][j]), fmaxf(sf[2][j], sf[3][j]));
      #pragma unroll
      for (int mm = 8; mm >= 1; mm >>= 1) tm = fmaxf(tm, __shfl_xor(tm, mm, 64));
      mnew[j] = fmaxf(m_prev[j], tm);
      fscale[j] = __expf(m_prev[j] - mnew[j]);
    }
    float rsum[4] = {0.f, 0.f, 0.f, 0.f};
    #pragma unroll
    for (int kf = 0; kf < 4; ++kf)
      #pragma unroll
      for (int j = 0; j < 4; ++j) {
        const float p = __expf(sf[kf][j] - mnew[j]);
        rsum[j] += p;
        Pl[w * (16 * LSTR) + (g4 * 4 + j) * LSTR + kf * 16 + r16] = (short)f2bf(p);
      }
    #pragma unroll
    for (int j = 0; j < 4; ++j) {
      float r = rsum[j];
      #pragma unroll
      for (int mm = 8; mm >= 1; mm >>= 1) r += __shfl_xor(r, mm, 64);
      l_acc[j] = l_acc[j] * fscale[j] + r;
      m_prev[j] = mnew[j];
    }
    #pragma unroll
    for (int hf = 0; hf < 4; ++hf)
      #pragma unroll
      for (int j = 0; j < 4; ++j) oacc[hf][j] *= fscale[j];

    // O += P V  — both operands now contiguous b128 LDS reads
    #pragma unroll
    for (int kk = 0; kk < 2; ++kk) {
      const short8 pf = *(const short8*)&Pl[w * (16 * LSTR) + r16 * LSTR + kk * 32 + g4 * 8];
      #pragma unroll
      for (int hf = 0; hf < 4; ++hf) {
        const short8 vf = *(const short8*)&Vl[(hf * 16 + r16) * LSTR + kk * 32 + g4 * 8];
        oacc[hf] = __builtin_amdgcn_mfma_f32_16x16x32_bf16(pf, vf, oacc[hf], 0, 0, 0);
      }
    }
    __syncthreads();
  }

  #pragma unroll
  for (int hf = 0; hf < 4; ++hf)
    #pragma unroll
    for (int j = 0; j < 4; ++j) {
      const float val = oacc[hf][j] / l_acc[j];
      const size_t orow = rowbase + qt * 64 + w * 16 + g4 * 4 + j;
      o[orow * DM + hh * 64 + hf * 16 + r16] = f2bf(val);
    }
}

// ---------------- launcher ----------------
extern "C" void kernel_launch(void* const* d_in, const int* in_sizes, int n_in,
                              void* d_out, int out_size, void* d_ws, size_t ws_size,
                              hipStream_t stream) {
  const float* x_in = (const float*)d_in[0];
  const float* Wq = (const float*)d_in[1];  const float* bq = (const float*)d_in[2];
  const float* Wk = (const float*)d_in[3];  const float* bk = (const float*)d_in[4];
  const float* Wv = (const float*)d_in[5];  const float* bv = (const float*)d_in[6];
  const float* Wo = (const float*)d_in[7];  const float* bo = (const float*)d_in[8];
  const float* W1 = (const float*)d_in[9];  const float* b1 = (const float*)d_in[10];
  const float* W2 = (const float*)d_in[11]; const float* b2 = (const float*)d_in[12];
  const float* ln1g = (const float*)d_in[13]; const float* ln1b = (const float*)d_in[14];
  const float* ln2g = (const float*)d_in[15]; const float* ln2b = (const float*)d_in[16];

  const size_t MB = 1u << 20;
  char* ws = (char*)d_ws;
  float*          x   = (float*)(ws + 0);                 // 16 MB fp32 residual
  unsigned short* h   = (unsigned short*)(ws + 16 * MB);  // 8 MB bf16 LN out
  unsigned short* qkv = (unsigned short*)(ws + 24 * MB);  // 24 MB bf16 [4096][3072]
  unsigned short* ob  = (unsigned short*)(ws + 48 * MB);  // 8 MB bf16 attn out
  unsigned short* f1  = (unsigned short*)(ws + 56 * MB);  // 32 MB bf16 ffn mid
  unsigned short* vt  = f1;                               // V^T reuses f1 (disjoint in time)
  unsigned short* wt  = (unsigned short*)(ws + 88 * MB);  // 8 MB bf16 transposed W
  float*          b3  = (float*)(ws + 96 * MB);           // 12 KB qkv bias

  hipMemcpyAsync(x, x_in, (size_t)MROWS * DM * sizeof(float),
                 hipMemcpyDeviceToDevice, stream);

  for (int i = 0; i < 4; ++i) {
    const size_t DD = (size_t)DM * DM;
    // --- attention sublayer ---
    ln_kernel<<<MROWS, 256, 0, stream>>>(x, ln1g + i * DM, ln1b + i * DM, h);
    transpose_cvt<<<dim3(32, 32), 256, 0, stream>>>(Wq + i * DD, wt,                 DM, DM);
    transpose_cvt<<<dim3(32, 32), 256, 0, stream>>>(Wk + i * DD, wt + 1024 * 1024,   DM, DM);
    transpose_cvt<<<dim3(32, 32), 256, 0, stream>>>(Wv + i * DD, wt + 2048 * 1024,   DM, DM);
    concat3<<<12, 256, 0, stream>>>(bq + i * DM, bk + i * DM, bv + i * DM, b3);
    gemm_bt<0, 0><<<dim3(QKVLD / 128, MROWS / 128), 256, 0, stream>>>(
        h, wt, b3, nullptr, nullptr, qkv, MROWS, QKVLD, DM);
    vtrans<<<dim3(2, 64, 32), 256, 0, stream>>>(qkv, vt);
    attn_kernel<<<dim3(SLEN / 64, 32), 256, 0, stream>>>(qkv, vt, ob);
    transpose_cvt<<<dim3(32, 32), 256, 0, stream>>>(Wo + i * DD, wt, DM, DM);
    gemm_bt<0, 1><<<dim3(DM / 128, MROWS / 128), 256, 0, stream>>>(
        ob, wt, bo + i * DM, x, x, nullptr, MROWS, DM, DM);
    // --- FFN sublayer ---
    ln_kernel<<<MROWS, 256, 0, stream>>>(x, ln2g + i * DM, ln2b + i * DM, h);
    transpose_cvt<<<dim3(128, 32), 256, 0, stream>>>(W1 + i * 4 * DD, wt, DM, 4 * DM);
    gemm_bt<1, 0><<<dim3(4 * DM / 128, MROWS / 128), 256, 0, stream>>>(
        h, wt, b1 + i * 4 * DM, nullptr, nullptr, f1, MROWS, 4 * DM, DM);
    transpose_cvt<<<dim3(32, 128), 256, 0, stream>>>(W2 + i * 4 * DD, wt, 4 * DM, DM);
    gemm_bt<0, 1><<<dim3(DM / 128, MROWS / 128), 256, 0, stream>>>(
        f1, wt, b2 + i * DM, x, x, nullptr, MROWS, DM, 4 * DM);
  }

  hipMemcpyAsync(d_out, x, (size_t)MROWS * DM * sizeof(float),
                 hipMemcpyDeviceToDevice, stream);
}

// Round 3
// 1455.329 us; speedup vs baseline: 1.1533x; 1.0580x over previous
//
#include <hip/hip_runtime.h>
#include <hip/hip_bf16.h>

#define DM 1024
#define SLEN 2048
#define MROWS 4096   // B*S
#define QKVLD 3072

typedef short  short8 __attribute__((ext_vector_type(8)));
typedef float  f32x4  __attribute__((ext_vector_type(4)));
typedef unsigned short u16x4 __attribute__((ext_vector_type(4)));

__device__ __forceinline__ unsigned short f2bf(float f) {
  __hip_bfloat16 h = __float2bfloat16(f);
  return __builtin_bit_cast(unsigned short, h);
}

__device__ __forceinline__ void gload16(const void* g, void* l) {
  __builtin_amdgcn_global_load_lds(
      (const __attribute__((address_space(1))) unsigned int*)g,
      (__attribute__((address_space(3))) unsigned int*)l, 16, 0, 0);
}

// ---------------- Weight transpose + fp32->bf16 convert ----------------
__global__ __launch_bounds__(256) void transpose_cvt(
    const float* __restrict__ W, unsigned short* __restrict__ Wt, int K, int N)
{
  __shared__ float t[32][33];
  const int k0 = blockIdx.y * 32, n0 = blockIdx.x * 32;
  const int tid = threadIdx.x;
  const int row = tid >> 3, c4 = (tid & 7) * 4;
  const float4 v = *(const float4*)&W[(size_t)(k0 + row) * N + n0 + c4];
  t[row][c4 + 0] = v.x; t[row][c4 + 1] = v.y;
  t[row][c4 + 2] = v.z; t[row][c4 + 3] = v.w;
  __syncthreads();
  u16x4 ov;
  #pragma unroll
  for (int j = 0; j < 4; ++j) ov[j] = f2bf(t[c4 + j][row]);
  *(u16x4*)&Wt[(size_t)(n0 + row) * K + k0 + c4] = ov;
}

// ---------------- V transpose: qkv V-cols -> Vt[bh][64][2048] (bf16) ----------------
__global__ __launch_bounds__(256) void vtrans(
    const unsigned short* __restrict__ qkv, unsigned short* __restrict__ vt)
{
  __shared__ unsigned short t[32][40];
  const int bh = blockIdx.z;                    // 0..31
  const int b = bh >> 4, h = bh & 15;
  const int s0 = blockIdx.y * 32, d0 = blockIdx.x * 32;
  const int tid = threadIdx.x;
  const int row = tid >> 3, c4 = (tid & 7) * 4;
  const u16x4 v = *(const u16x4*)&qkv[(size_t)(b * SLEN + s0 + row) * QKVLD + 2048 + h * 64 + d0 + c4];
  t[row][c4 + 0] = v[0]; t[row][c4 + 1] = v[1];
  t[row][c4 + 2] = v[2]; t[row][c4 + 3] = v[3];
  __syncthreads();
  u16x4 ov;
  #pragma unroll
  for (int j = 0; j < 4; ++j) ov[j] = t[c4 + j][row];
  *(u16x4*)&vt[((size_t)bh * 64 + d0 + row) * SLEN + s0 + c4] = ov;
}

// ---------------- LayerNorm (fp32 in, bf16 out) ----------------
__global__ __launch_bounds__(256) void ln_kernel(
    const float* __restrict__ x, const float* __restrict__ g,
    const float* __restrict__ b, unsigned short* __restrict__ h)
{
  const int row = blockIdx.x, tid = threadIdx.x;
  const float4 v = ((const float4*)(x + (size_t)row * DM))[tid];
  float s  = v.x + v.y + v.z + v.w;
  float ss = v.x * v.x + v.y * v.y + v.z * v.z + v.w * v.w;
  #pragma unroll
  for (int m = 32; m >= 1; m >>= 1) {
    s  += __shfl_xor(s,  m, 64);
    ss += __shfl_xor(ss, m, 64);
  }
  __shared__ float red[8];
  const int w = tid >> 6, lane = tid & 63;
  if (lane == 0) { red[w] = s; red[4 + w] = ss; }
  __syncthreads();
  s  = red[0] + red[1] + red[2] + red[3];
  ss = red[4] + red[5] + red[6] + red[7];
  const float mu  = s * (1.f / DM);
  const float var = ss * (1.f / DM) - mu * mu;
  const float rs  = rsqrtf(var + 1e-5f);
  const float4 gv = ((const float4*)g)[tid];
  const float4 bv = ((const float4*)b)[tid];
  u16x4 o;
  o[0] = f2bf((v.x - mu) * rs * gv.x + bv.x);
  o[1] = f2bf((v.y - mu) * rs * gv.y + bv.y);
  o[2] = f2bf((v.z - mu) * rs * gv.z + bv.z);
  o[3] = f2bf((v.w - mu) * rs * gv.w + bv.w);
  ((u16x4*)(h + (size_t)row * DM))[tid] = o;
}

// ---------------- bias concat (bq|bk|bv -> 3072) ----------------
__global__ void concat3(const float* __restrict__ a, const float* __restrict__ b,
                        const float* __restrict__ c, float* __restrict__ out)
{
  const int i = blockIdx.x * 256 + threadIdx.x;
  out[i] = (i < 1024) ? a[i] : (i < 2048 ? b[i - 1024] : c[i - 2048]);
}

// ---------------- GEMM: C[M][N] = A[M][K](bf16) @ Bt[N][K]^T(bf16) + bias ----------------
template<int RELU, int RESID>
__global__ __launch_bounds__(256) void gemm_bt(
    const unsigned short* __restrict__ A,
    const unsigned short* __restrict__ Bt,
    const float* __restrict__ bias,
    const float* __restrict__ res,
    float* __restrict__ outf,
    unsigned short* __restrict__ outb,
    int M, int N, int K)
{
  __shared__ short Al[128 * 32];
  __shared__ short Bl[128 * 32];
  const int tid = threadIdx.x;
  const int w = tid >> 6, lane = tid & 63;
  const int m0 = blockIdx.y * 128, n0 = blockIdx.x * 128;
  const int wr = (w >> 1) * 64, wc = (w & 1) * 64;
  const int r16 = lane & 15, g4 = lane >> 4;

  f32x4 acc[4][4];
  #pragma unroll
  for (int i = 0; i < 4; ++i)
    #pragma unroll
    for (int j = 0; j < 4; ++j) acc[i][j] = (f32x4){0.f, 0.f, 0.f, 0.f};

  for (int kt = 0; kt < K; kt += 32) {
    #pragma unroll
    for (int i = 0; i < 2; ++i) {
      const int chunk = (i * 4 + w) * 64 + lane;   // 0..511
      const int row = chunk >> 2, off = (chunk & 3) * 8;
      gload16(&A[(size_t)(m0 + row) * K + kt + off], &Al[chunk * 8]);
      gload16(&Bt[(size_t)(n0 + row) * K + kt + off], &Bl[chunk * 8]);
    }
    __syncthreads();
    short8 af[4], bfr[4];
    #pragma unroll
    for (int mi = 0; mi < 4; ++mi)
      af[mi] = *(const short8*)&Al[(wr + mi * 16 + r16) * 32 + g4 * 8];
    #pragma unroll
    for (int ni = 0; ni < 4; ++ni)
      bfr[ni] = *(const short8*)&Bl[(wc + ni * 16 + r16) * 32 + g4 * 8];
    #pragma unroll
    for (int mi = 0; mi < 4; ++mi)
      #pragma unroll
      for (int ni = 0; ni < 4; ++ni)
        acc[mi][ni] = __builtin_amdgcn_mfma_f32_16x16x32_bf16(af[mi], bfr[ni], acc[mi][ni], 0, 0, 0);
    __syncthreads();
  }

  #pragma unroll
  for (int ni = 0; ni < 4; ++ni) {
    const int col = n0 + wc + ni * 16 + r16;
    const float bv = bias[col];
    #pragma unroll
    for (int mi = 0; mi < 4; ++mi) {
      #pragma unroll
      for (int j = 0; j < 4; ++j) {
        const int row = m0 + wr + mi * 16 + g4 * 4 + j;
        float v = acc[mi][ni][j] + bv;
        if (RELU) v = fmaxf(v, 0.f);
        const size_t idx = (size_t)row * N + col;
        if (RESID) outf[idx] = res[idx] + v;
        else       outb[idx] = f2bf(v);
      }
    }
  }
}

// ---------------- Flash attention v3 ----------------
// grid (S/128 q-tiles, B*H). 4 waves x 32 q-rows (2 m-frags each).
// K/V double-buffered in LDS, async reg-staged; stride 68 (bank-friendly).
// Row-sum of P computed by MFMA with ones-B (no sum butterflies).
#define LSTR 68
#define PSTR 68
#define NT   (SLEN / 64)
__global__ __launch_bounds__(256) void attn_kernel(
    const unsigned short* __restrict__ qkv,   // [B*S][3072] (q|k|v)
    const unsigned short* __restrict__ vt,    // [B*H][64][2048]
    unsigned short* __restrict__ o)           // [B*S][1024]
{
  __shared__ short Kl[2][64 * LSTR];
  __shared__ short Vl[2][64 * LSTR];   // transposed: [d][key]
  __shared__ short Pl[128 * PSTR];     // per-wave 32-row regions
  const int tid = threadIdx.x;
  const int w = tid >> 6, lane = tid & 63;
  const int r16 = lane & 15, g4 = lane >> 4;
  const int qt = blockIdx.x;
  const int bh = blockIdx.y;
  const int hh = bh & 15;
  const size_t rowbase = (size_t)(bh >> 4) * SLEN;
  const short* qp = (const short*)qkv;
  const short* vp = (const short*)(vt + (size_t)bh * 64 * SLEN);

  // Q fragments: 2 m-frags x 2 k-blocks
  short8 qf[2][2];
  #pragma unroll
  for (int mi = 0; mi < 2; ++mi) {
    const size_t qrow = rowbase + qt * 128 + w * 32 + mi * 16 + r16;
    #pragma unroll
    for (int kk = 0; kk < 2; ++kk)
      qf[mi][kk] = *(const short8*)&qp[qrow * QKVLD + hh * 64 + kk * 32 + g4 * 8];
  }

  short8 ones;
  #pragma unroll
  for (int i = 0; i < 8; ++i) ones[i] = (short)0x3F80;  // bf16 1.0

  // staging: each thread owns rows srow, srow+32 (16B at soff)
  const int srow = tid >> 3;
  const int soff = (tid & 7) * 8;
  short8 kreg[2], vreg[2];

  // prologue: tile 0
  #pragma unroll
  for (int i = 0; i < 2; ++i) {
    const int row = srow + i * 32;
    kreg[i] = *(const short8*)&qp[(rowbase + row) * QKVLD + 1024 + hh * 64 + soff];
    vreg[i] = *(const short8*)&vp[(size_t)row * SLEN + soff];
  }
  #pragma unroll
  for (int i = 0; i < 2; ++i) {
    const int row = srow + i * 32;
    *(short8*)&Kl[0][row * LSTR + soff] = kreg[i];
    *(short8*)&Vl[0][row * LSTR + soff] = vreg[i];
  }

  f32x4 oacc[2][4];
  f32x4 l_vec[2];
  float m_prev[2][4];
  #pragma unroll
  for (int mi = 0; mi < 2; ++mi) {
    l_vec[mi] = (f32x4){0.f, 0.f, 0.f, 0.f};
    #pragma unroll
    for (int hf = 0; hf < 4; ++hf) oacc[mi][hf] = (f32x4){0.f, 0.f, 0.f, 0.f};
    #pragma unroll
    for (int j = 0; j < 4; ++j) m_prev[mi][j] = -1e30f;
  }

  for (int kt = 0; kt < NT; ++kt) {
    const int cur = kt & 1;
    // issue next tile's global loads early (latency hides under compute)
    if (kt + 1 < NT) {
      #pragma unroll
      for (int i = 0; i < 2; ++i) {
        const int row = srow + i * 32;
        kreg[i] = *(const short8*)&qp[(rowbase + (kt + 1) * 64 + row) * QKVLD + 1024 + hh * 64 + soff];
        vreg[i] = *(const short8*)&vp[(size_t)row * SLEN + (kt + 1) * 64 + soff];
      }
    }
    __syncthreads();

    // ---- QK^T ----
    short8 kfr[4][2];
    #pragma unroll
    for (int kf = 0; kf < 4; ++kf)
      #pragma unroll
      for (int kk = 0; kk < 2; ++kk)
        kfr[kf][kk] = *(const short8*)&Kl[cur][(kf * 16 + r16) * LSTR + kk * 32 + g4 * 8];
    f32x4 sf[2][4];
    #pragma unroll
    for (int mi = 0; mi < 2; ++mi)
      #pragma unroll
      for (int kf = 0; kf < 4; ++kf) {
        f32x4 a = (f32x4){0.f, 0.f, 0.f, 0.f};
        #pragma unroll
        for (int kk = 0; kk < 2; ++kk)
          a = __builtin_amdgcn_mfma_f32_16x16x32_bf16(qf[mi][kk], kfr[kf][kk], a, 0, 0, 0);
        sf[mi][kf] = a * 0.125f;
      }

    // ---- online softmax (max only; sums via MFMA below) ----
    float fscale[2][4];
    #pragma unroll
    for (int mi = 0; mi < 2; ++mi)
      #pragma unroll
      for (int j = 0; j < 4; ++j) {
        float tm = fmaxf(fmaxf(sf[mi][0][j], sf[mi][1][j]), fmaxf(sf[mi][2][j], sf[mi][3][j]));
        #pragma unroll
        for (int mm = 8; mm >= 1; mm >>= 1) tm = fmaxf(tm, __shfl_xor(tm, mm, 64));
        const float mn = fmaxf(m_prev[mi][j], tm);
        fscale[mi][j] = __expf(m_prev[mi][j] - mn);
        m_prev[mi][j] = mn;
      }
    #pragma unroll
    for (int mi = 0; mi < 2; ++mi)
      #pragma unroll
      for (int kf = 0; kf < 4; ++kf)
        #pragma unroll
        for (int j = 0; j < 4; ++j) {
          const float p = __expf(sf[mi][kf][j] - m_prev[mi][j]);
          Pl[(w * 32 + mi * 16 + g4 * 4 + j) * PSTR + kf * 16 + r16] = (short)f2bf(p);
        }
    #pragma unroll
    for (int mi = 0; mi < 2; ++mi)
      #pragma unroll
      for (int j = 0; j < 4; ++j) {
        l_vec[mi][j] *= fscale[mi][j];
        #pragma unroll
        for (int hf = 0; hf < 4; ++hf) oacc[mi][hf][j] *= fscale[mi][j];
      }

    // ---- PV + row-sums ----
    short8 vf[2][4];
    #pragma unroll
    for (int kk = 0; kk < 2; ++kk)
      #pragma unroll
      for (int hf = 0; hf < 4; ++hf)
        vf[kk][hf] = *(const short8*)&Vl[cur][(hf * 16 + r16) * LSTR + kk * 32 + g4 * 8];
    short8 pf[2][2];
    #pragma unroll
    for (int mi = 0; mi < 2; ++mi)
      #pragma unroll
      for (int kk = 0; kk < 2; ++kk)
        pf[mi][kk] = *(const short8*)&Pl[(w * 32 + mi * 16 + r16) * PSTR + kk * 32 + g4 * 8];
    #pragma unroll
    for (int mi = 0; mi < 2; ++mi) {
      #pragma unroll
      for (int kk = 0; kk < 2; ++kk) {
        l_vec[mi] = __builtin_amdgcn_mfma_f32_16x16x32_bf16(pf[mi][kk], ones, l_vec[mi], 0, 0, 0);
        #pragma unroll
        for (int hf = 0; hf < 4; ++hf)
          oacc[mi][hf] = __builtin_amdgcn_mfma_f32_16x16x32_bf16(pf[mi][kk], vf[kk][hf], oacc[mi][hf], 0, 0, 0);
      }
    }

    // commit next tile into the other buffer (no extra barrier needed)
    if (kt + 1 < NT) {
      #pragma unroll
      for (int i = 0; i < 2; ++i) {
        const int row = srow + i * 32;
        *(short8*)&Kl[cur ^ 1][row * LSTR + soff] = kreg[i];
        *(short8*)&Vl[cur ^ 1][row * LSTR + soff] = vreg[i];
      }
    }
  }

  #pragma unroll
  for (int mi = 0; mi < 2; ++mi)
    #pragma unroll
    for (int j = 0; j < 4; ++j) {
      const float rl = 1.f / l_vec[mi][j];
      const size_t orow = rowbase + qt * 128 + w * 32 + mi * 16 + g4 * 4 + j;
      #pragma unroll
      for (int hf = 0; hf < 4; ++hf)
        o[orow * DM + hh * 64 + hf * 16 + r16] = f2bf(oacc[mi][hf][j] * rl);
    }
}

// ---------------- launcher ----------------
extern "C" void kernel_launch(void* const* d_in, const int* in_sizes, int n_in,
                              void* d_out, int out_size, void* d_ws, size_t ws_size,
                              hipStream_t stream) {
  const float* x_in = (const float*)d_in[0];
  const float* Wq = (const float*)d_in[1];  const float* bq = (const float*)d_in[2];
  const float* Wk = (const float*)d_in[3];  const float* bk = (const float*)d_in[4];
  const float* Wv = (const float*)d_in[5];  const float* bv = (const float*)d_in[6];
  const float* Wo = (const float*)d_in[7];  const float* bo = (const float*)d_in[8];
  const float* W1 = (const float*)d_in[9];  const float* b1 = (const float*)d_in[10];
  const float* W2 = (const float*)d_in[11]; const float* b2 = (const float*)d_in[12];
  const float* ln1g = (const float*)d_in[13]; const float* ln1b = (const float*)d_in[14];
  const float* ln2g = (const float*)d_in[15]; const float* ln2b = (const float*)d_in[16];

  const size_t MB = 1u << 20;
  char* ws = (char*)d_ws;
  float*          x   = (float*)(ws + 0);                 // 16 MB fp32 residual
  unsigned short* h   = (unsigned short*)(ws + 16 * MB);  // 8 MB bf16 LN out
  unsigned short* qkv = (unsigned short*)(ws + 24 * MB);  // 24 MB bf16 [4096][3072]
  unsigned short* ob  = (unsigned short*)(ws + 48 * MB);  // 8 MB bf16 attn out
  unsigned short* f1  = (unsigned short*)(ws + 56 * MB);  // 32 MB bf16 ffn mid
  unsigned short* vt  = f1;                               // V^T reuses f1 (disjoint in time)
  unsigned short* wt  = (unsigned short*)(ws + 88 * MB);  // 8 MB bf16 transposed W
  float*          b3  = (float*)(ws + 96 * MB);           // 12 KB qkv bias

  hipMemcpyAsync(x, x_in, (size_t)MROWS * DM * sizeof(float),
                 hipMemcpyDeviceToDevice, stream);

  for (int i = 0; i < 4; ++i) {
    const size_t DD = (size_t)DM * DM;
    // --- attention sublayer ---
    ln_kernel<<<MROWS, 256, 0, stream>>>(x, ln1g + i * DM, ln1b + i * DM, h);
    transpose_cvt<<<dim3(32, 32), 256, 0, stream>>>(Wq + i * DD, wt,                 DM, DM);
    transpose_cvt<<<dim3(32, 32), 256, 0, stream>>>(Wk + i * DD, wt + 1024 * 1024,   DM, DM);
    transpose_cvt<<<dim3(32, 32), 256, 0, stream>>>(Wv + i * DD, wt + 2048 * 1024,   DM, DM);
    concat3<<<12, 256, 0, stream>>>(bq + i * DM, bk + i * DM, bv + i * DM, b3);
    gemm_bt<0, 0><<<dim3(QKVLD / 128, MROWS / 128), 256, 0, stream>>>(
        h, wt, b3, nullptr, nullptr, qkv, MROWS, QKVLD, DM);
    vtrans<<<dim3(2, 64, 32), 256, 0, stream>>>(qkv, vt);
    attn_kernel<<<dim3(SLEN / 128, 32), 256, 0, stream>>>(qkv, vt, ob);
    transpose_cvt<<<dim3(32, 32), 256, 0, stream>>>(Wo + i * DD, wt, DM, DM);
    gemm_bt<0, 1><<<dim3(DM / 128, MROWS / 128), 256, 0, stream>>>(
        ob, wt, bo + i * DM, x, x, nullptr, MROWS, DM, DM);
    // --- FFN sublayer ---
    ln_kernel<<<MROWS, 256, 0, stream>>>(x, ln2g + i * DM, ln2b + i * DM, h);
    transpose_cvt<<<dim3(128, 32), 256, 0, stream>>>(W1 + i * 4 * DD, wt, DM, 4 * DM);
    gemm_bt<1, 0><<<dim3(4 * DM / 128, MROWS / 128), 256, 0, stream>>>(
        h, wt, b1 + i * 4 * DM, nullptr, nullptr, f1, MROWS, 4 * DM, DM);
    transpose_cvt<<<dim3(32, 128), 256, 0, stream>>>(W2 + i * 4 * DD, wt, 4 * DM, DM);
    gemm_bt<0, 1><<<dim3(DM / 128, MROWS / 128), 256, 0, stream>>>(
        f1, wt, b2 + i * DM, x, x, nullptr, MROWS, DM, 4 * DM);
  }

  hipMemcpyAsync(d_out, x, (size_t)MROWS * DM * sizeof(float),
                 hipMemcpyDeviceToDevice, stream);
}

// Round 4
// 1397.675 us; speedup vs baseline: 1.2009x; 1.0413x over previous
//
#include <hip/hip_runtime.h>
#include <hip/hip_bf16.h>

#define DM 1024
#define SLEN 2048
#define MROWS 4096   // B*S
#define QKVLD 3072

typedef short  short8 __attribute__((ext_vector_type(8)));
typedef float  f32x4  __attribute__((ext_vector_type(4)));
typedef unsigned short u16x4 __attribute__((ext_vector_type(4)));

__device__ __forceinline__ unsigned short f2bf(float f) {
  __hip_bfloat16 h = __float2bfloat16(f);
  return __builtin_bit_cast(unsigned short, h);
}

__device__ __forceinline__ void gload16(const void* g, void* l) {
  __builtin_amdgcn_global_load_lds(
      (const __attribute__((address_space(1))) unsigned int*)g,
      (__attribute__((address_space(3))) unsigned int*)l, 16, 0, 0);
}

// ---------------- Weight transpose + fp32->bf16 convert ----------------
__global__ __launch_bounds__(256) void transpose_cvt(
    const float* __restrict__ W, unsigned short* __restrict__ Wt, int K, int N)
{
  __shared__ float t[32][33];
  const int k0 = blockIdx.y * 32, n0 = blockIdx.x * 32;
  const int tid = threadIdx.x;
  const int row = tid >> 3, c4 = (tid & 7) * 4;
  const float4 v = *(const float4*)&W[(size_t)(k0 + row) * N + n0 + c4];
  t[row][c4 + 0] = v.x; t[row][c4 + 1] = v.y;
  t[row][c4 + 2] = v.z; t[row][c4 + 3] = v.w;
  __syncthreads();
  u16x4 ov;
  #pragma unroll
  for (int j = 0; j < 4; ++j) ov[j] = f2bf(t[c4 + j][row]);
  *(u16x4*)&Wt[(size_t)(n0 + row) * K + k0 + c4] = ov;
}

// ---------------- LayerNorm (fp32 in, bf16 out) ----------------
__global__ __launch_bounds__(256) void ln_kernel(
    const float* __restrict__ x, const float* __restrict__ g,
    const float* __restrict__ b, unsigned short* __restrict__ h)
{
  const int row = blockIdx.x, tid = threadIdx.x;
  const float4 v = ((const float4*)(x + (size_t)row * DM))[tid];
  float s  = v.x + v.y + v.z + v.w;
  float ss = v.x * v.x + v.y * v.y + v.z * v.z + v.w * v.w;
  #pragma unroll
  for (int m = 32; m >= 1; m >>= 1) {
    s  += __shfl_xor(s,  m, 64);
    ss += __shfl_xor(ss, m, 64);
  }
  __shared__ float red[8];
  const int w = tid >> 6, lane = tid & 63;
  if (lane == 0) { red[w] = s; red[4 + w] = ss; }
  __syncthreads();
  s  = red[0] + red[1] + red[2] + red[3];
  ss = red[4] + red[5] + red[6] + red[7];
  const float mu  = s * (1.f / DM);
  const float var = ss * (1.f / DM) - mu * mu;
  const float rs  = rsqrtf(var + 1e-5f);
  const float4 gv = ((const float4*)g)[tid];
  const float4 bv = ((const float4*)b)[tid];
  u16x4 o;
  o[0] = f2bf((v.x - mu) * rs * gv.x + bv.x);
  o[1] = f2bf((v.y - mu) * rs * gv.y + bv.y);
  o[2] = f2bf((v.z - mu) * rs * gv.z + bv.z);
  o[3] = f2bf((v.w - mu) * rs * gv.w + bv.w);
  ((u16x4*)(h + (size_t)row * DM))[tid] = o;
}

// ---------------- bias concat for all layers (bq|bk|bv -> [4][3072]) ----------------
__global__ void concat3all(const float* __restrict__ a, const float* __restrict__ b,
                           const float* __restrict__ c, float* __restrict__ out)
{
  const int i = blockIdx.x * 256 + threadIdx.x;   // 0..4*3072-1
  const int l = i / 3072, r = i % 3072;
  out[i] = (r < 1024) ? a[l * 1024 + r]
         : (r < 2048) ? b[l * 1024 + r - 1024]
                      : c[l * 1024 + r - 2048];
}

// ---------------- GEMM: C[M][N] = A[M][K](bf16) @ Bt[N][K]^T(bf16) + bias ----------------
// VOUT: cols >= 2048 are V columns -> written transposed to vt[bh][d][s].
template<int RELU, int RESID, int VOUT>
__global__ __launch_bounds__(256) void gemm_bt(
    const unsigned short* __restrict__ A,
    const unsigned short* __restrict__ Bt,
    const float* __restrict__ bias,
    const float* __restrict__ res,
    float* __restrict__ outf,
    unsigned short* __restrict__ outb,
    unsigned short* __restrict__ vt,
    int M, int N, int K)
{
  __shared__ short Al[128 * 32];
  __shared__ short Bl[128 * 32];
  const int tid = threadIdx.x;
  const int w = tid >> 6, lane = tid & 63;
  const int m0 = blockIdx.y * 128, n0 = blockIdx.x * 128;
  const int wr = (w >> 1) * 64, wc = (w & 1) * 64;
  const int r16 = lane & 15, g4 = lane >> 4;

  f32x4 acc[4][4];
  #pragma unroll
  for (int i = 0; i < 4; ++i)
    #pragma unroll
    for (int j = 0; j < 4; ++j) acc[i][j] = (f32x4){0.f, 0.f, 0.f, 0.f};

  for (int kt = 0; kt < K; kt += 32) {
    #pragma unroll
    for (int i = 0; i < 2; ++i) {
      const int chunk = (i * 4 + w) * 64 + lane;   // 0..511
      const int row = chunk >> 2, off = (chunk & 3) * 8;
      gload16(&A[(size_t)(m0 + row) * K + kt + off], &Al[chunk * 8]);
      gload16(&Bt[(size_t)(n0 + row) * K + kt + off], &Bl[chunk * 8]);
    }
    __syncthreads();
    short8 af[4], bfr[4];
    #pragma unroll
    for (int mi = 0; mi < 4; ++mi)
      af[mi] = *(const short8*)&Al[(wr + mi * 16 + r16) * 32 + g4 * 8];
    #pragma unroll
    for (int ni = 0; ni < 4; ++ni)
      bfr[ni] = *(const short8*)&Bl[(wc + ni * 16 + r16) * 32 + g4 * 8];
    #pragma unroll
    for (int mi = 0; mi < 4; ++mi)
      #pragma unroll
      for (int ni = 0; ni < 4; ++ni)
        acc[mi][ni] = __builtin_amdgcn_mfma_f32_16x16x32_bf16(af[mi], bfr[ni], acc[mi][ni], 0, 0, 0);
    __syncthreads();
  }

  #pragma unroll
  for (int ni = 0; ni < 4; ++ni) {
    const int col = n0 + wc + ni * 16 + r16;
    const float bv = bias[col];
    #pragma unroll
    for (int mi = 0; mi < 4; ++mi) {
      const int row = m0 + wr + mi * 16 + g4 * 4;   // j = 0..3 below
      float v4[4];
      #pragma unroll
      for (int j = 0; j < 4; ++j) {
        float v = acc[mi][ni][j] + bv;
        if (RELU) v = fmaxf(v, 0.f);
        v4[j] = v;
      }
      if (VOUT && col >= 2048) {
        // V column -> vt[(b*16+h)*64+d][s], 4 consecutive s packed
        const int hh = (col - 2048) >> 6, dd = (col - 2048) & 63;
        const int bb = row >> 11, ss = row & 2047;
        u16x4 pv;
        #pragma unroll
        for (int j = 0; j < 4; ++j) pv[j] = f2bf(v4[j]);
        *(u16x4*)&vt[(((size_t)bb * 16 + hh) * 64 + dd) * SLEN + ss] = pv;
      } else {
        #pragma unroll
        for (int j = 0; j < 4; ++j) {
          const size_t idx = (size_t)(row + j) * N + col;
          if (RESID) outf[idx] = res[idx] + v4[j];
          else       outb[idx] = f2bf(v4[j]);
        }
      }
    }
  }
}

// ---------------- Flash attention v4 ----------------
// grid (S/128 q-tiles, B*H). 4 waves x 32 q-rows (2 m-frags each).
// K/V double-buffered LDS, reg-staged; exp2-domain softmax; defer-max (THR=8);
// row-sums via ones-MFMA; setprio around MFMA clusters.
#define LSTR 68
#define PSTR 68
#define NT   (SLEN / 64)
#define SC   0.18033688f   // 0.125 * log2(e)
__global__ __launch_bounds__(256) void attn_kernel(
    const unsigned short* __restrict__ qkv,   // [B*S][3072] (q|k|v)
    const unsigned short* __restrict__ vt,    // [B*H][64][2048]
    unsigned short* __restrict__ o)           // [B*S][1024]
{
  __shared__ short Kl[2][64 * LSTR];
  __shared__ short Vl[2][64 * LSTR];   // transposed: [d][key]
  __shared__ short Pl[128 * PSTR];     // per-wave 32-row regions
  const int tid = threadIdx.x;
  const int w = tid >> 6, lane = tid & 63;
  const int r16 = lane & 15, g4 = lane >> 4;
  const int qt = blockIdx.x;
  const int bh = blockIdx.y;
  const int hh = bh & 15;
  const size_t rowbase = (size_t)(bh >> 4) * SLEN;
  const short* qp = (const short*)qkv;
  const short* vp = (const short*)(vt + (size_t)bh * 64 * SLEN);

  short8 qf[2][2];
  #pragma unroll
  for (int mi = 0; mi < 2; ++mi) {
    const size_t qrow = rowbase + qt * 128 + w * 32 + mi * 16 + r16;
    #pragma unroll
    for (int kk = 0; kk < 2; ++kk)
      qf[mi][kk] = *(const short8*)&qp[qrow * QKVLD + hh * 64 + kk * 32 + g4 * 8];
  }

  short8 ones;
  #pragma unroll
  for (int i = 0; i < 8; ++i) ones[i] = (short)0x3F80;  // bf16 1.0

  const int srow = tid >> 3;
  const int soff = (tid & 7) * 8;
  short8 kreg[2], vreg[2];

  #pragma unroll
  for (int i = 0; i < 2; ++i) {
    const int row = srow + i * 32;
    kreg[i] = *(const short8*)&qp[(rowbase + row) * QKVLD + 1024 + hh * 64 + soff];
    vreg[i] = *(const short8*)&vp[(size_t)row * SLEN + soff];
  }
  #pragma unroll
  for (int i = 0; i < 2; ++i) {
    const int row = srow + i * 32;
    *(short8*)&Kl[0][row * LSTR + soff] = kreg[i];
    *(short8*)&Vl[0][row * LSTR + soff] = vreg[i];
  }

  f32x4 oacc[2][4];
  f32x4 l_vec[2];
  float m_prev[2][4];
  #pragma unroll
  for (int mi = 0; mi < 2; ++mi) {
    l_vec[mi] = (f32x4){0.f, 0.f, 0.f, 0.f};
    #pragma unroll
    for (int hf = 0; hf < 4; ++hf) oacc[mi][hf] = (f32x4){0.f, 0.f, 0.f, 0.f};
    #pragma unroll
    for (int j = 0; j < 4; ++j) m_prev[mi][j] = -1e30f;
  }

  for (int kt = 0; kt < NT; ++kt) {
    const int cur = kt & 1;
    if (kt + 1 < NT) {
      #pragma unroll
      for (int i = 0; i < 2; ++i) {
        const int row = srow + i * 32;
        kreg[i] = *(const short8*)&qp[(rowbase + (kt + 1) * 64 + row) * QKVLD + 1024 + hh * 64 + soff];
        vreg[i] = *(const short8*)&vp[(size_t)row * SLEN + (kt + 1) * 64 + soff];
      }
    }
    __syncthreads();

    // ---- QK^T (scores in log2-scaled domain) ----
    short8 kfr[4][2];
    #pragma unroll
    for (int kf = 0; kf < 4; ++kf)
      #pragma unroll
      for (int kk = 0; kk < 2; ++kk)
        kfr[kf][kk] = *(const short8*)&Kl[cur][(kf * 16 + r16) * LSTR + kk * 32 + g4 * 8];
    f32x4 sf[2][4];
    __builtin_amdgcn_s_setprio(1);
    #pragma unroll
    for (int mi = 0; mi < 2; ++mi)
      #pragma unroll
      for (int kf = 0; kf < 4; ++kf) {
        f32x4 a = (f32x4){0.f, 0.f, 0.f, 0.f};
        #pragma unroll
        for (int kk = 0; kk < 2; ++kk)
          a = __builtin_amdgcn_mfma_f32_16x16x32_bf16(qf[mi][kk], kfr[kf][kk], a, 0, 0, 0);
        sf[mi][kf] = a * SC;
      }
    __builtin_amdgcn_s_setprio(0);

    // ---- online softmax max-tracking with defer (THR=8 in log2 domain) ----
    float tmv[2][4];
    bool need = false;
    #pragma unroll
    for (int mi = 0; mi < 2; ++mi)
      #pragma unroll
      for (int j = 0; j < 4; ++j) {
        float tm = fmaxf(fmaxf(sf[mi][0][j], sf[mi][1][j]), fmaxf(sf[mi][2][j], sf[mi][3][j]));
        #pragma unroll
        for (int mm = 8; mm >= 1; mm >>= 1) tm = fmaxf(tm, __shfl_xor(tm, mm, 64));
        tmv[mi][j] = tm;
        need = need || (tm > m_prev[mi][j] + 8.f);
      }
    if (__ballot(need)) {
      #pragma unroll
      for (int mi = 0; mi < 2; ++mi)
        #pragma unroll
        for (int j = 0; j < 4; ++j) {
          const float mn = fmaxf(m_prev[mi][j], tmv[mi][j]);
          const float fs = exp2f(m_prev[mi][j] - mn);
          m_prev[mi][j] = mn;
          l_vec[mi][j] *= fs;
          #pragma unroll
          for (int hf = 0; hf < 4; ++hf) oacc[mi][hf][j] *= fs;
        }
    }
    #pragma unroll
    for (int mi = 0; mi < 2; ++mi)
      #pragma unroll
      for (int kf = 0; kf < 4; ++kf)
        #pragma unroll
        for (int j = 0; j < 4; ++j) {
          const float p = exp2f(sf[mi][kf][j] - m_prev[mi][j]);
          Pl[(w * 32 + mi * 16 + g4 * 4 + j) * PSTR + kf * 16 + r16] = (short)f2bf(p);
        }

    // ---- PV + row-sums ----
    short8 vf[2][4];
    #pragma unroll
    for (int kk = 0; kk < 2; ++kk)
      #pragma unroll
      for (int hf = 0; hf < 4; ++hf)
        vf[kk][hf] = *(const short8*)&Vl[cur][(hf * 16 + r16) * LSTR + kk * 32 + g4 * 8];
    short8 pf[2][2];
    #pragma unroll
    for (int mi = 0; mi < 2; ++mi)
      #pragma unroll
      for (int kk = 0; kk < 2; ++kk)
        pf[mi][kk] = *(const short8*)&Pl[(w * 32 + mi * 16 + r16) * PSTR + kk * 32 + g4 * 8];
    __builtin_amdgcn_s_setprio(1);
    #pragma unroll
    for (int mi = 0; mi < 2; ++mi) {
      #pragma unroll
      for (int kk = 0; kk < 2; ++kk) {
        l_vec[mi] = __builtin_amdgcn_mfma_f32_16x16x32_bf16(pf[mi][kk], ones, l_vec[mi], 0, 0, 0);
        #pragma unroll
        for (int hf = 0; hf < 4; ++hf)
          oacc[mi][hf] = __builtin_amdgcn_mfma_f32_16x16x32_bf16(pf[mi][kk], vf[kk][hf], oacc[mi][hf], 0, 0, 0);
      }
    }
    __builtin_amdgcn_s_setprio(0);

    if (kt + 1 < NT) {
      #pragma unroll
      for (int i = 0; i < 2; ++i) {
        const int row = srow + i * 32;
        *(short8*)&Kl[cur ^ 1][row * LSTR + soff] = kreg[i];
        *(short8*)&Vl[cur ^ 1][row * LSTR + soff] = vreg[i];
      }
    }
  }

  #pragma unroll
  for (int mi = 0; mi < 2; ++mi)
    #pragma unroll
    for (int j = 0; j < 4; ++j) {
      const float rl = 1.f / l_vec[mi][j];
      const size_t orow = rowbase + qt * 128 + w * 32 + mi * 16 + g4 * 4 + j;
      #pragma unroll
      for (int hf = 0; hf < 4; ++hf)
        o[orow * DM + hh * 64 + hf * 16 + r16] = f2bf(oacc[mi][hf][j] * rl);
    }
}

// ---------------- launcher ----------------
extern "C" void kernel_launch(void* const* d_in, const int* in_sizes, int n_in,
                              void* d_out, int out_size, void* d_ws, size_t ws_size,
                              hipStream_t stream) {
  const float* x_in = (const float*)d_in[0];
  const float* Wq = (const float*)d_in[1];  const float* bq = (const float*)d_in[2];
  const float* Wk = (const float*)d_in[3];  const float* bk = (const float*)d_in[4];
  const float* Wv = (const float*)d_in[5];  const float* bv = (const float*)d_in[6];
  const float* Wo = (const float*)d_in[7];  const float* bo = (const float*)d_in[8];
  const float* W1 = (const float*)d_in[9];  const float* b1 = (const float*)d_in[10];
  const float* W2 = (const float*)d_in[11]; const float* b2 = (const float*)d_in[12];
  const float* ln1g = (const float*)d_in[13]; const float* ln1b = (const float*)d_in[14];
  const float* ln2g = (const float*)d_in[15]; const float* ln2b = (const float*)d_in[16];

  const size_t MB = 1u << 20;
  char* ws = (char*)d_ws;
  float*          x   = (float*)(ws + 0);                 // 16 MB fp32 residual
  unsigned short* h   = (unsigned short*)(ws + 16 * MB);  // 8 MB bf16 LN out
  unsigned short* qkv = (unsigned short*)(ws + 24 * MB);  // 24 MB bf16 [4096][3072]
  unsigned short* ob  = (unsigned short*)(ws + 48 * MB);  // 8 MB bf16 attn out
  unsigned short* f1  = (unsigned short*)(ws + 56 * MB);  // 32 MB bf16 ffn mid
  unsigned short* vt  = f1;                               // V^T reuses f1 (disjoint in time)
  unsigned short* wt  = (unsigned short*)(ws + 88 * MB);  // 8 MB bf16 transposed W
  float*          b3  = (float*)(ws + 96 * MB);           // 48 KB qkv bias (all layers)

  hipMemcpyAsync(x, x_in, (size_t)MROWS * DM * sizeof(float),
                 hipMemcpyDeviceToDevice, stream);
  concat3all<<<48, 256, 0, stream>>>(bq, bk, bv, b3);

  for (int i = 0; i < 4; ++i) {
    const size_t DD = (size_t)DM * DM;
    // --- attention sublayer ---
    ln_kernel<<<MROWS, 256, 0, stream>>>(x, ln1g + i * DM, ln1b + i * DM, h);
    transpose_cvt<<<dim3(32, 32), 256, 0, stream>>>(Wq + i * DD, wt,                 DM, DM);
    transpose_cvt<<<dim3(32, 32), 256, 0, stream>>>(Wk + i * DD, wt + 1024 * 1024,   DM, DM);
    transpose_cvt<<<dim3(32, 32), 256, 0, stream>>>(Wv + i * DD, wt + 2048 * 1024,   DM, DM);
    gemm_bt<0, 0, 1><<<dim3(QKVLD / 128, MROWS / 128), 256, 0, stream>>>(
        h, wt, b3 + i * QKVLD, nullptr, nullptr, qkv, vt, MROWS, QKVLD, DM);
    attn_kernel<<<dim3(SLEN / 128, 32), 256, 0, stream>>>(qkv, vt, ob);
    transpose_cvt<<<dim3(32, 32), 256, 0, stream>>>(Wo + i * DD, wt, DM, DM);
    gemm_bt<0, 1, 0><<<dim3(DM / 128, MROWS / 128), 256, 0, stream>>>(
        ob, wt, bo + i * DM, x, x, nullptr, nullptr, MROWS, DM, DM);
    // --- FFN sublayer ---
    ln_kernel<<<MROWS, 256, 0, stream>>>(x, ln2g + i * DM, ln2b + i * DM, h);
    transpose_cvt<<<dim3(128, 32), 256, 0, stream>>>(W1 + i * 4 * DD, wt, DM, 4 * DM);
    gemm_bt<1, 0, 0><<<dim3(4 * DM / 128, MROWS / 128), 256, 0, stream>>>(
        h, wt, b1 + i * 4 * DM, nullptr, nullptr, f1, nullptr, MROWS, 4 * DM, DM);
    transpose_cvt<<<dim3(32, 128), 256, 0, stream>>>(W2 + i * 4 * DD, wt, 4 * DM, DM);
    gemm_bt<0, 1, 0><<<dim3(DM / 128, MROWS / 128), 256, 0, stream>>>(
        f1, wt, b2 + i * DM, x, x, nullptr, nullptr, MROWS, DM, 4 * DM);
  }

  hipMemcpyAsync(d_out, x, (size_t)MROWS * DM * sizeof(float),
                 hipMemcpyDeviceToDevice, stream);
}